// Round 2
// baseline (426.083 us; speedup 1.0000x reference)
//
#include <hip/hip_runtime.h>

// Problem: x[16,64,256,256] f32 -> out[B=16, s0=2, s1=16, s2=16, c=32, h=16, w=16]
// out[b][i][j][k][ci][hi][wi] = x[b][i*32+ci][j*16+hi][k*16+wi]
//
// Tile per block: fixed (b, Cidx=i*32+ci, j). Input slab [hi=16][W=256] is a
// contiguous 16 KiB run. Output is 16 chunks (one per k) of 1 KiB contiguous.
// Stage through LDS in output-linear order with an XOR bank swizzle.

__global__ __launch_bounds__(256) void split_map1_kernel(
    const float4* __restrict__ in, float4* __restrict__ out) {
    __shared__ float4 lds[1024];  // 16 KiB

    const int bid  = blockIdx.x;
    const int tid  = threadIdx.x;
    const int j    = bid & 15;          // s1 index
    const int Cidx = (bid >> 4) & 63;   // full C index = i*32 + ci
    const int b    = bid >> 10;         // batch

    // Input base in float4 units: ((b*64 + Cidx)*256 + j*16) * 256 floats / 4
    const int in_base = (b * 64 + Cidx) * 16384 + j * 1024;

    // Stage: global (input-linear, coalesced 16 KiB) -> LDS (output-linear, swizzled)
#pragma unroll
    for (int it = 0; it < 4; ++it) {
        const int o = it * 256 + tid;             // input-linear float4 unit
        const float4 v = in[in_base + o];
        const int hi  = o >> 6;                   // row within tile (W = 64 units)
        const int k   = (o >> 2) & 15;            // s2 index
        const int wi4 = o & 3;                    // float4 within w-run
        const int u   = (k << 6) | (hi << 2) | wi4;          // output-linear unit
        const int us  = u ^ (((k & 1) << 2) | ((k >> 1) & 3)); // bank swizzle (involution)
        lds[us] = v;
    }
    __syncthreads();

    const int i  = Cidx >> 5;
    const int ci = Cidx & 31;
    // out float4 base for k=0: ((((b*2+i)*16 + j)*16 + 0)*32 + ci) * 256 floats / 4
    const int out_base0 = (((((b * 2 + i) * 16 + j) * 16) * 32) + ci) << 6;

    // Drain: LDS (output-linear, conflict-free) -> global (coalesced 1 KiB per wave)
#pragma unroll
    for (int it = 0; it < 4; ++it) {
        const int u  = it * 256 + tid;            // output-linear float4 unit
        const int k  = u >> 6;                    // constant per wave
        const int us = u ^ (((k & 1) << 2) | ((k >> 1) & 3));
        const float4 v = lds[us];
        out[out_base0 + (k << 11) + (u & 63)] = v;
    }
}

extern "C" void kernel_launch(void* const* d_in, const int* in_sizes, int n_in,
                              void* d_out, int out_size, void* d_ws, size_t ws_size,
                              hipStream_t stream) {
    const float4* in  = (const float4*)d_in[0];
    float4*       out = (float4*)d_out;
    // Tiles: b(16) * Cidx(64) * j(16) = 16384 blocks, 256 threads each.
    split_map1_kernel<<<dim3(16384), dim3(256), 0, stream>>>(in, out);
}